// Round 11
// baseline (378.390 us; speedup 1.0000x reference)
//
#include <hip/hip_runtime.h>

// WS layout: base (R5-proven) ~156 MB; fp8 extras Xf8+Awf8 +33 MB appended.
// Host guards on ws_size: if extras don't fit, fall back to bf16 score path.
// R2: k_front = prep+uk+bias, k_mid = wgemm+cast. R3/R4: grid-stride cast.
// R6: HW v_cvt_pk_fp8_f32 + score8 2-phase dbuf. R8: un-fuse REGRESSED.
// R10: NT feat loads -> 360.2 us (downstream L3 win; k_mid itself flat at
// 2.3 TB/s across SIX variants -> stream-mix cap hypothesis).
// R11: fp8 path drops the Xb stream from k_mid (3 streams -> 2) and k_attn
// reads fp32 feat directly (NT). Tests the stream hypothesis; precision
// strictly improves (Y from fp32 X). bf16 fallback path unchanged.

typedef unsigned short u16;
typedef unsigned char u8;
typedef __attribute__((ext_vector_type(8))) __bf16 bf16x8;
typedef __attribute__((ext_vector_type(4))) float floatx4;
typedef __attribute__((ext_vector_type(16))) float floatx16;
typedef __attribute__((ext_vector_type(8))) int intx8;

__device__ __forceinline__ u16 f2bf(float f) {
    unsigned u = __float_as_uint(f);
    unsigned r = (u + 0x7FFFu + ((u >> 16) & 1u)) >> 16;
    return (u16)r;
}

// float -> OCP e4m3fn, RNE, saturate. Layout [s:1][e:4][m:3]: exp at BIT 3.
// Software path; hot loops use HW v_cvt_pk_fp8_f32 when available.
__device__ __forceinline__ unsigned f2e4m3(float x) {
    unsigned u = __float_as_uint(x);
    unsigned s = (u >> 31) << 7;
    float a = __uint_as_float(u & 0x7FFFFFFFu);
    if (a >= 448.f) return s | 0x7E;
    if (a < 0.03125f) {  // codes 0..16 are exactly k * 2^-9
        unsigned k = (unsigned)__float2int_rn(a * 512.f);
        return s | k;
    }
    unsigned b = __float_as_uint(a);
    unsigned lsb = (b >> 20) & 1u;
    b += 0x0007FFFFu + lsb;  // RNE to 3 mantissa bits (carry fixes exponent)
    unsigned ex = (b >> 23) - 120u;      // fp32 bias 127 -> e4m3 bias 7
    unsigned man = (b >> 20) & 7u;
    return s | (ex << 3) | man;
}

// 4x f32 -> packed e4m3 dword. HW packed cvt (2 inst) if the builtin exists.
__device__ __forceinline__ unsigned pack_fp8x4(floatx4 w) {
#if __has_builtin(__builtin_amdgcn_cvt_pk_fp8_f32)
    unsigned r = __builtin_amdgcn_cvt_pk_fp8_f32(w.x, w.y, 0u, false);
    r = __builtin_amdgcn_cvt_pk_fp8_f32(w.z, w.w, r, true);
    return r;
#else
    return f2e4m3(w.x) | (f2e4m3(w.y) << 8) |
           (f2e4m3(w.z) << 16) | (f2e4m3(w.w) << 24);
#endif
}

__device__ __forceinline__ void load_lds16(const void* g, void* l) {
    __builtin_amdgcn_global_load_lds(
        (const __attribute__((address_space(1))) void*)g,
        (__attribute__((address_space(3))) void*)l, 16, 0, 0);
}

__device__ __forceinline__ void unpack8(uint4 v, float* f) {
    f[0] = __uint_as_float(v.x << 16);
    f[1] = __uint_as_float(v.x & 0xFFFF0000u);
    f[2] = __uint_as_float(v.y << 16);
    f[3] = __uint_as_float(v.y & 0xFFFF0000u);
    f[4] = __uint_as_float(v.z << 16);
    f[5] = __uint_as_float(v.z & 0xFFFF0000u);
    f[6] = __uint_as_float(v.w << 16);
    f[7] = __uint_as_float(v.w & 0xFFFF0000u);
}

// ---------------------------------------------------------------------------
// k_front: weight-side prep, one launch.
//   ids [0,4096): z=0 WkT=Wk^T, z=1 WqT=Wq^T, z=2 WvT=Wv^T, z=3 Wob=cast(Wo)
//   ids [4096,4160): uk partials  u[h] += sum_o Wk[o,h]*bq[o]   (u pre-zeroed)
//   ids [4160,5184): cvec[j] = sum_o Wo[j,o]*bv[o] + bo[j]
__global__ __launch_bounds__(256) void k_front(const float* __restrict__ Wq,
                                               const float* __restrict__ Wk,
                                               const float* __restrict__ Wv,
                                               const float* __restrict__ Wo,
                                               const float* __restrict__ bq,
                                               const float* __restrict__ bv,
                                               const float* __restrict__ bo,
                                               u16* __restrict__ WqT,
                                               u16* __restrict__ WkT,
                                               u16* __restrict__ WvT,
                                               u16* __restrict__ Wob,
                                               float* __restrict__ u,
                                               float* __restrict__ cvec, int H) {
    __shared__ float t[32][33];
    __shared__ float red[4];
    const int id = blockIdx.x;
    if (id < 4096) {
        const int z = id >> 10;
        const int bx = (id & 31) * 32, by = ((id >> 5) & 31) * 32;
        const float* in = (z == 0) ? Wk : (z == 1) ? Wq : (z == 2) ? Wv : Wo;
        u16* out = (z == 0) ? WkT : (z == 1) ? WqT : (z == 2) ? WvT : Wob;
        const int x = threadIdx.x & 31, ty = threadIdx.x >> 5;
        if (z < 3) {
            for (int y = ty; y < 32; y += 8)
                t[y][x] = in[(size_t)(by + y) * H + bx + x];
            __syncthreads();
            for (int y = ty; y < 32; y += 8)
                out[(size_t)(bx + y) * H + by + x] = f2bf(t[x][y]);
        } else {
            for (int y = ty; y < 32; y += 8)
                out[(size_t)(by + y) * H + bx + x] =
                    f2bf(in[(size_t)(by + y) * H + bx + x]);
        }
    } else if (id < 4160) {
        const int r = id - 4096;                 // (H/256)=4 x-blocks, 16 y
        const int h = (r & 3) * 256 + threadIdx.x;
        const int chunk = H / 16, o0 = (r >> 2) * chunk;
        float s = 0.f;
        for (int o = o0; o < o0 + chunk; ++o) s += bq[o] * Wk[(size_t)o * H + h];
        atomicAdd(&u[h], s);
    } else {
        const int j = id - 4160;
        const int lane = threadIdx.x & 63, wv = threadIdx.x >> 6;
        float s = 0.f;
        for (int o = threadIdx.x; o < H; o += 256)
            s += Wo[(size_t)j * H + o] * bv[o];
        for (int off = 32; off > 0; off >>= 1) s += __shfl_down(s, off);
        if (lane == 0) red[wv] = s;
        __syncthreads();
        if (threadIdx.x == 0) cvec[j] = red[0] + red[1] + red[2] + red[3] + bo[j];
    }
}

// ---------------------------------------------------------------------------
// bf16 BT-GEMM body (R2/R5-verified). OUTMODE 0: fp32+bias; 1: bf16(+bias);
// 2: dual-write bf16 (Cp) AND fp8(32x) (Cp8, skipped if null).
struct GemmLds { u16 As[128 * 32]; u16 Bs[128 * 32]; };

template <int OUTMODE>
__device__ __forceinline__ void gemm_body(GemmLds& S,
                                          const u16* __restrict__ A,
                                          const u16* __restrict__ Bw,
                                          void* __restrict__ Cp,
                                          u8* __restrict__ Cp8,
                                          const float* __restrict__ bias,
                                          int M, int N, int K,
                                          int bx, int by) {
    u16* As = S.As;
    u16* Bs = S.Bs;
    const int tid = threadIdx.x, lane = tid & 63, wv = tid >> 6;
    const int m0 = bx * 128, n0 = by * 128;
    const int wm = (wv >> 1) * 64, wn = (wv & 1) * 64;

    floatx4 acc[4][4];
#pragma unroll
    for (int i = 0; i < 4; ++i)
#pragma unroll
        for (int j = 0; j < 4; ++j) acc[i][j] = (floatx4){0.f, 0.f, 0.f, 0.f};

    const int srow = lane >> 2;
    const int scol = (((lane & 3) ^ ((lane >> 3) & 3)) * 8);
    const u16* gA = A + (size_t)(m0 + srow) * K + scol;
    const u16* gB = Bw + (size_t)(n0 + srow) * K + scol;
    const int r = lane & 15, q = lane >> 4;
    const int cph = q ^ ((r >> 1) & 3);

    for (int kt = 0; kt < K; kt += 32) {
#pragma unroll
        for (int c = 0; c < 2; ++c) {
            int chunk = wv * 2 + c;
            load_lds16(gA + (size_t)(chunk * 16) * K + kt, &As[chunk * 16 * 32]);
            load_lds16(gB + (size_t)(chunk * 16) * K + kt, &Bs[chunk * 16 * 32]);
        }
        __syncthreads();
        bf16x8 af[4], bfr[4];
#pragma unroll
        for (int i = 0; i < 4; ++i) {
            af[i] = *(const bf16x8*)&As[(wm + i * 16 + r) * 32 + cph * 8];
            bfr[i] = *(const bf16x8*)&Bs[(wn + i * 16 + r) * 32 + cph * 8];
        }
#pragma unroll
        for (int i = 0; i < 4; ++i)
#pragma unroll
            for (int j = 0; j < 4; ++j)
                acc[i][j] = __builtin_amdgcn_mfma_f32_16x16x32_bf16(af[i], bfr[j], acc[i][j], 0, 0, 0);
        __syncthreads();
    }

    const int cc = lane & 15, cr = (lane >> 4) * 4;
#pragma unroll
    for (int i = 0; i < 4; ++i)
#pragma unroll
        for (int j = 0; j < 4; ++j) {
            int col = n0 + wn + j * 16 + cc;
            float badd = bias ? bias[col] : 0.f;
#pragma unroll
            for (int r0 = 0; r0 < 4; ++r0) {
                int row = m0 + wm + i * 16 + cr + r0;
                float v = acc[i][j][r0] + badd;
                if (OUTMODE == 0) ((float*)Cp)[(size_t)row * N + col] = v;
                else ((u16*)Cp)[(size_t)row * N + col] = f2bf(v);
                if (OUTMODE == 2 && Cp8)
                    Cp8[(size_t)row * N + col] = (u8)f2e4m3(32.f * v);
            }
        }
}

// ---------------------------------------------------------------------------
// k_mid: weight GEMMs + feature cast in ONE launch (R6-proven structure).
//   ids [0,128): GEMM blocks. z=0: Aw = bf16(Wk^T Wq) (+ Awf8 = fp8(32x));
//                z=1: Wov = Wo Wv.
//   ids [128, 128+2048): grid-stride cast, CH=4096 floats/block-iter,
//   4 independent NT float4 loads in flight. R11: fp8 path passes Xb=null ->
//   only the Xf8 stream is written (3 streams -> 2, stream-cap test).
__global__ __launch_bounds__(256) void k_mid(const float* __restrict__ feat,
                                             u16* __restrict__ Xb,
                                             u8* __restrict__ Xf8, long n,
                                             const u16* __restrict__ WkT,
                                             const u16* __restrict__ WqT,
                                             u16* __restrict__ Aw,
                                             u8* __restrict__ Awf8,
                                             const u16* __restrict__ Wob,
                                             const u16* __restrict__ WvT,
                                             u16* __restrict__ Wov, int H) {
    __shared__ __align__(16) GemmLds S;
    const int id = blockIdx.x;
    if (id < 128) {
        const int z = id >> 6, bx = (id & 63) & 7, by = (id & 63) >> 3;
        if (z == 0)
            gemm_body<2>(S, WkT, WqT, Aw, Awf8, nullptr, H, H, H, bx, by);
        else
            gemm_body<1>(S, Wob, WvT, Wov, nullptr, nullptr, H, H, H, bx, by);
        return;
    }
    const int tid = threadIdx.x;
    const long nCast = (long)(gridDim.x - 128);
    const long CH = 4096;  // floats per block-iter (256 thr x 16)
    for (long s = (long)(id - 128) * CH; s < n; s += nCast * CH) {
        const floatx4* src = (const floatx4*)(feat + s) + tid;
        floatx4 v[4];
#pragma unroll
        for (int k = 0; k < 4; ++k)
            v[k] = __builtin_nontemporal_load(src + k * 256);  // 4 in flight, NT
        if (Xb) {
            ushort4* db = (ushort4*)(Xb + s) + tid;
#pragma unroll
            for (int k = 0; k < 4; ++k) {
                ushort4 o;
                o.x = f2bf(v[k].x); o.y = f2bf(v[k].y);
                o.z = f2bf(v[k].z); o.w = f2bf(v[k].w);
                db[k * 256] = o;
            }
        }
        if (Xf8) {
            unsigned* df = (unsigned*)(Xf8 + s) + tid;
#pragma unroll
            for (int k = 0; k < 4; ++k) df[k * 256] = pack_fp8x4(v[k]);
        }
    }
}

// bf16 fallback score GEMM: G = bf16(X Aw^T + uk)
__global__ __launch_bounds__(256) void k_score(const u16* __restrict__ X,
                                               const u16* __restrict__ Aw,
                                               u16* __restrict__ G,
                                               const float* __restrict__ uk,
                                               int Mr, int N, int K) {
    __shared__ __align__(16) GemmLds S;
    gemm_body<1>(S, X, Aw, G, nullptr, uk, Mr, N, K, blockIdx.x, blockIdx.y);
}

// out = Y @ Wov^T + cvec (fp32 out)
__global__ __launch_bounds__(256) void k_out(const u16* __restrict__ A,
                                             const u16* __restrict__ Bw,
                                             float* __restrict__ C,
                                             const float* __restrict__ bias,
                                             int M, int N, int K) {
    __shared__ __align__(16) GemmLds S;
    gemm_body<0>(S, A, Bw, C, nullptr, bias, M, N, K, blockIdx.x, blockIdx.y);
}

// ---------------------------------------------------------------------------
// MX-fp8 score GEMM via mfma_scale_f32_32x32x64_f8f6f4, unit E8M0 scales.
// 2-phase double-buffer (R6): prefetch tile t+1 into buf^1 BEFORE computing
// tile t; ONE __syncthreads per tile (implicit vmcnt(0)+lgkmcnt(0) drain).
// A/B lane layout: m = lane&31, k = (lane>>5)*32 + byte. C/D (guide-verified):
// col = lane&31, row = (reg&3) + 8*(reg>>2) + 4*(lane>>5).
// XCD-aware bijective swizzle (nwg=2048, %8==0).
// G[r,h'] = 32*(sum_h X[r,h]*Aw[h',h] + uk[h']), bf16 out.
__global__ __launch_bounds__(256) void k_score8(const u8* __restrict__ Af8,
                                                const u8* __restrict__ Bf8,
                                                u16* __restrict__ G,
                                                const float* __restrict__ uk,
                                                int Mr, int N, int K) {
    __shared__ __align__(16) u8 As[2][128 * 64];
    __shared__ __align__(16) u8 Bs[2][128 * 64];
    const int tid = threadIdx.x, lane = tid & 63, wv = tid >> 6;

    // XCD swizzle: orig%8 == XCD id under round-robin dispatch.
    const int nbx = gridDim.x;                       // 8
    const int nwg = nbx * gridDim.y;                 // 2048 (divisible by 8)
    const int orig = blockIdx.y * nbx + blockIdx.x;
    const int cpx = nwg >> 3;                        // blocks per XCD
    const int id = (orig & 7) * cpx + (orig >> 3);
    const int n0 = (id % nbx) * 128, m0 = (id / nbx) * 128;
    const int wm = (wv >> 1) * 64, wn = (wv & 1) * 64;

    floatx16 acc[2][2];
#pragma unroll
    for (int i = 0; i < 2; ++i)
#pragma unroll
        for (int j = 0; j < 2; ++j)
            acc[i][j] = (floatx16){0.f, 0.f, 0.f, 0.f, 0.f, 0.f, 0.f, 0.f,
                                   0.f, 0.f, 0.f, 0.f, 0.f, 0.f, 0.f, 0.f};

    const int srow = lane >> 2;
    const int scol = 16 * ((lane & 3) ^ ((lane >> 3) & 3));
    const u8* gA = Af8 + (size_t)(m0 + srow) * K + scol;
    const u8* gB = Bf8 + (size_t)(n0 + srow) * K + scol;

    // frag read geometry: lane needs k-bytes [q2*32, q2*32+32) of row r32,
    // i.e. 16B chunks {2q2, 2q2+1}, XOR'd by the staging swizzle (r32>>1)&3.
    const int r32 = lane & 31, q2 = lane >> 5;
    const int sw = (r32 >> 1) & 3;
    const int c0 = (2 * q2) ^ sw, c1 = (2 * q2 + 1) ^ sw;

    union frag32 { intx8 v; uint4 q[2]; };

    auto stage = [&](int buf, int kt) {
#pragma unroll
        for (int c = 0; c < 2; ++c) {
            int chunk = wv * 2 + c;
            load_lds16(gA + (size_t)(chunk * 16) * K + kt, &As[buf][chunk * 16 * 64]);
            load_lds16(gB + (size_t)(chunk * 16) * K + kt, &Bs[buf][chunk * 16 * 64]);
        }
    };

    stage(0, 0);
    __syncthreads();
    int cur = 0;
    for (int kt = 0; kt < K; kt += 64) {
        if (kt + 64 < K) stage(cur ^ 1, kt + 64);  // next tile in flight
        frag32 fa[2], fb[2];
#pragma unroll
        for (int i = 0; i < 2; ++i) {
            const u8* pa = &As[cur][(wm + i * 32 + r32) * 64];
            const u8* pb = &Bs[cur][(wn + i * 32 + r32) * 64];
            fa[i].q[0] = *(const uint4*)(pa + c0 * 16);
            fa[i].q[1] = *(const uint4*)(pa + c1 * 16);
            fb[i].q[0] = *(const uint4*)(pb + c0 * 16);
            fb[i].q[1] = *(const uint4*)(pb + c1 * 16);
        }
#pragma unroll
        for (int i = 0; i < 2; ++i)
#pragma unroll
            for (int j = 0; j < 2; ++j)
                acc[i][j] = __builtin_amdgcn_mfma_scale_f32_32x32x64_f8f6f4(
                    fa[i].v, fb[j].v, acc[i][j], 0, 0,
                    0, 0x7F7F7F7F, 0, 0x7F7F7F7F);
        __syncthreads();  // drains vmcnt (next tile landed) + syncs ds_reads
        cur ^= 1;
    }

    const int cc = lane & 31, rbase = 4 * (lane >> 5);
#pragma unroll
    for (int i = 0; i < 2; ++i)
#pragma unroll
        for (int j = 0; j < 2; ++j) {
            int col = n0 + wn + j * 32 + cc;
            float badd = 32.f * uk[col];
#pragma unroll
            for (int reg = 0; reg < 16; ++reg) {
                int row = m0 + wm + i * 32 + (reg & 3) + 8 * (reg >> 2) + rbase;
                G[(size_t)row * N + col] = f2bf(acc[i][j][reg] + badd);
            }
        }
}

// ---------------------------------------------------------------------------
// Per-batch attention, one wave per batch.
// gscale folds G's scale into the softmax: bf16 G -> conf/32; fp8 G -> conf/1024.
// k_attn: bf16 X path (fallback). k_attn_f32: reads fp32 feat directly
// (fp8 path, R11) — NT loads, Y computed at full fp32 X precision.
__global__ __launch_bounds__(256) void k_attn(const u16* __restrict__ G,
                                              const u16* __restrict__ X,
                                              const float* __restrict__ conf,
                                              u16* __restrict__ Y, float gscale,
                                              int H) {
    const int lane = threadIdx.x & 63, wv = threadIdx.x >> 6;
    const int b = blockIdx.x * 4 + wv;
    const u16* Gb = G + (size_t)b * 4 * H;
    const u16* Xb = X + (size_t)b * 4 * H;

    uint4 xraw[2][4];
    float s[16];
#pragma unroll
    for (int t = 0; t < 16; ++t) s[t] = 0.f;

#pragma unroll
    for (int c = 0; c < 2; ++c) {
        const int off = c * 512 + lane * 8;
#pragma unroll
        for (int rr = 0; rr < 4; ++rr)
            xraw[c][rr] = *(const uint4*)(Xb + rr * H + off);
        float xv[4][8];
#pragma unroll
        for (int rr = 0; rr < 4; ++rr) unpack8(xraw[c][rr], xv[rr]);
#pragma unroll
        for (int m = 0; m < 4; ++m) {
            uint4 gl = *(const uint4*)(Gb + m * H + off);
            float gv[8];
            unpack8(gl, gv);
#pragma unroll
            for (int n = 0; n < 4; ++n) {
                float a = 0.f;
#pragma unroll
                for (int j = 0; j < 8; ++j) a += gv[j] * xv[n][j];
                s[m * 4 + n] += a;
            }
        }
    }
#pragma unroll
    for (int t = 0; t < 16; ++t) {
#pragma unroll
        for (int mask = 32; mask; mask >>= 1) s[t] += __shfl_xor(s[t], mask);
    }
    float w[4] = {0.f, 0.f, 0.f, 0.f};
#pragma unroll
    for (int m = 0; m < 4; ++m) {
        float cm = conf[(size_t)b * 4 + m] * gscale;
        float sc[4], mx = -1e30f;
#pragma unroll
        for (int n = 0; n < 4; ++n) {
            sc[n] = s[m * 4 + n] * cm;
            mx = fmaxf(mx, sc[n]);
        }
        float e[4], ssum = 0.f;
#pragma unroll
        for (int n = 0; n < 4; ++n) { e[n] = __expf(sc[n] - mx); ssum += e[n]; }
        float inv = 0.25f / ssum;
#pragma unroll
        for (int n = 0; n < 4; ++n) w[n] += e[n] * inv;
    }
#pragma unroll
    for (int c = 0; c < 2; ++c) {
        const int off = c * 512 + lane * 8;
        float xv[4][8];
#pragma unroll
        for (int rr = 0; rr < 4; ++rr) unpack8(xraw[c][rr], xv[rr]);
        float y[8];
#pragma unroll
        for (int j = 0; j < 8; ++j)
            y[j] = w[0] * xv[0][j] + w[1] * xv[1][j] + w[2] * xv[2][j] + w[3] * xv[3][j];
        uint4 res;
        res.x = (unsigned)f2bf(y[0]) | ((unsigned)f2bf(y[1]) << 16);
        res.y = (unsigned)f2bf(y[2]) | ((unsigned)f2bf(y[3]) << 16);
        res.z = (unsigned)f2bf(y[4]) | ((unsigned)f2bf(y[5]) << 16);
        res.w = (unsigned)f2bf(y[6]) | ((unsigned)f2bf(y[7]) << 16);
        *(uint4*)(Y + (size_t)b * H + off) = res;
    }
}

__global__ __launch_bounds__(256) void k_attn_f32(const u16* __restrict__ G,
                                                  const float* __restrict__ X,
                                                  const float* __restrict__ conf,
                                                  u16* __restrict__ Y,
                                                  float gscale, int H) {
    const int lane = threadIdx.x & 63, wv = threadIdx.x >> 6;
    const int b = blockIdx.x * 4 + wv;
    const u16* Gb = G + (size_t)b * 4 * H;
    const float* Xf = X + (size_t)b * 4 * H;

    floatx4 xs[2][4][2];  // [half][row][2x float4] — X kept in registers
    float s[16];
#pragma unroll
    for (int t = 0; t < 16; ++t) s[t] = 0.f;

#pragma unroll
    for (int c = 0; c < 2; ++c) {
        const int off = c * 512 + lane * 8;
#pragma unroll
        for (int rr = 0; rr < 4; ++rr) {
            const floatx4* p = (const floatx4*)(Xf + (size_t)rr * H + off);
            xs[c][rr][0] = __builtin_nontemporal_load(p);      // feat read-once
            xs[c][rr][1] = __builtin_nontemporal_load(p + 1);
        }
#pragma unroll
        for (int m = 0; m < 4; ++m) {
            uint4 gl = *(const uint4*)(Gb + m * H + off);
            float gv[8];
            unpack8(gl, gv);
#pragma unroll
            for (int n = 0; n < 4; ++n) {
                float a = 0.f;
#pragma unroll
                for (int j = 0; j < 8; ++j)
                    a += gv[j] * xs[c][n][j >> 2][j & 3];
                s[m * 4 + n] += a;
            }
        }
    }
#pragma unroll
    for (int t = 0; t < 16; ++t) {
#pragma unroll
        for (int mask = 32; mask; mask >>= 1) s[t] += __shfl_xor(s[t], mask);
    }
    float w[4] = {0.f, 0.f, 0.f, 0.f};
#pragma unroll
    for (int m = 0; m < 4; ++m) {
        float cm = conf[(size_t)b * 4 + m] * gscale;
        float sc[4], mx = -1e30f;
#pragma unroll
        for (int n = 0; n < 4; ++n) {
            sc[n] = s[m * 4 + n] * cm;
            mx = fmaxf(mx, sc[n]);
        }
        float e[4], ssum = 0.f;
#pragma unroll
        for (int n = 0; n < 4; ++n) { e[n] = __expf(sc[n] - mx); ssum += e[n]; }
        float inv = 0.25f / ssum;
#pragma unroll
        for (int n = 0; n < 4; ++n) w[n] += e[n] * inv;
    }
#pragma unroll
    for (int c = 0; c < 2; ++c) {
        const int off = c * 512 + lane * 8;
        float y[8];
#pragma unroll
        for (int j = 0; j < 8; ++j)
            y[j] = w[0] * xs[c][0][j >> 2][j & 3] + w[1] * xs[c][1][j >> 2][j & 3] +
                   w[2] * xs[c][2][j >> 2][j & 3] + w[3] * xs[c][3][j >> 2][j & 3];
        uint4 res;
        res.x = (unsigned)f2bf(y[0]) | ((unsigned)f2bf(y[1]) << 16);
        res.y = (unsigned)f2bf(y[2]) | ((unsigned)f2bf(y[3]) << 16);
        res.z = (unsigned)f2bf(y[4]) | ((unsigned)f2bf(y[5]) << 16);
        res.w = (unsigned)f2bf(y[6]) | ((unsigned)f2bf(y[7]) << 16);
        *(uint4*)(Y + (size_t)b * H + off) = res;
    }
}

// ---------------------------------------------------------------------------
extern "C" void kernel_launch(void* const* d_in, const int* in_sizes, int n_in,
                              void* d_out, int out_size, void* d_ws, size_t ws_size,
                              hipStream_t stream) {
    const int H = 1024, M = 4;
    const int B = in_sizes[0] / (H * M);
    const long BMH = (long)B * M * H;

    const float* feat = (const float*)d_in[0];
    const float* conf = (const float*)d_in[1];
    const float* Wq = (const float*)d_in[2];
    const float* bq = (const float*)d_in[3];
    const float* Wk = (const float*)d_in[4];
    const float* Wv = (const float*)d_in[6];
    const float* bv = (const float*)d_in[7];
    const float* Wo = (const float*)d_in[8];
    const float* bo = (const float*)d_in[9];

    char* ws = (char*)d_ws;
    size_t off = 0;
    auto alloc = [&](size_t bytes) {
        void* p = ws + off;
        off += (bytes + 255) & ~(size_t)255;
        return p;
    };
    // base (R5-proven footprint)
    u16* Xb    = (u16*)alloc((size_t)BMH * 2);   //  64 MB (fallback path only)
    u16* G     = (u16*)alloc((size_t)BMH * 2);   //  64 MB
    u16* Yb    = (u16*)alloc((size_t)B * H * 2); //  16 MB
    u16* WkT   = (u16*)alloc((size_t)H * H * 2);
    u16* WqT   = (u16*)alloc((size_t)H * H * 2);
    u16* WvT   = (u16*)alloc((size_t)H * H * 2);
    u16* Wob   = (u16*)alloc((size_t)H * H * 2);
    u16* Aw    = (u16*)alloc((size_t)H * H * 2);
    u16* Wov   = (u16*)alloc((size_t)H * H * 2);
    float* u    = (float*)alloc((size_t)H * 4);
    float* cvec = (float*)alloc((size_t)H * 4);
    // fp8 extras (+33 MB) — only used if they fit
    u8* Xf8  = (u8*)alloc((size_t)BMH);
    u8* Awf8 = (u8*)alloc((size_t)H * H);
    const bool use_fp8 = (off <= ws_size);
    (void)n_in; (void)out_size;

    // 1. weight-side prep (one launch) — u zeroed first for the uk atomics
    hipMemsetAsync(u, 0, (size_t)H * 4, stream);
    k_front<<<4096 + 64 + H, 256, 0, stream>>>(
        Wq, Wk, Wv, Wo, bq, bv, bo, WqT, WkT, WvT, Wob, u, cvec, H);

    // 2. weight GEMMs overlapped with grid-stride feature cast (one launch)
    //    fp8 path: Xb stream dropped (2-stream cast); fallback: Xb only.
    k_mid<<<128 + 2048, 256, 0, stream>>>(
        feat, use_fp8 ? nullptr : Xb, use_fp8 ? Xf8 : nullptr, BMH,
        WkT, WqT, Aw, use_fp8 ? Awf8 : nullptr, Wob, WvT, Wov, H);

    // 3. score GEMM
    if (use_fp8) {
        k_score8<<<dim3(H / 128, B * M / 128), 256, 0, stream>>>(
            Xf8, Awf8, G, u, B * M, H, H);
    } else {
        k_score<<<dim3(B * M / 128, H / 128), 256, 0, stream>>>(
            Xb, Aw, G, u, B * M, H, H);
    }

    // 4. attention -> Y  (fp8 G carries a 32x scale: 1/(32*32) vs 1/32)
    if (use_fp8) {
        k_attn_f32<<<B / 4, 256, 0, stream>>>(G, feat, conf, Yb,
                                              0.0009765625f, H);
    } else {
        k_attn<<<B / 4, 256, 0, stream>>>(G, Xb, conf, Yb, 0.03125f, H);
    }

    // 5. out = Y @ Wov^T + cvec
    k_out<<<dim3(B / 128, H / 128), 256, 0, stream>>>(Yb, Wov, (float*)d_out, cvec, B, H, H);
}

// Round 12
// 357.515 us; speedup vs baseline: 1.0584x; 1.0584x over previous
//
#include <hip/hip_runtime.h>

// WS layout: base (R5-proven) ~156 MB; fp8 extras Xf8+Awf8 +33 MB appended.
// Host guards on ws_size: if extras don't fit, fall back to bf16 score path.
// R2: k_front = prep+uk+bias, k_mid = wgemm+cast. R3/R4: grid-stride cast.
// R6: HW v_cvt_pk_fp8_f32 + score8 2-phase dbuf. R8: un-fuse REGRESSED (+32).
// R10: NT feat loads -> 360.2 us BEST (downstream L3 win).
// R11: Xb-elimination + attn-from-fp32-feat REGRESSED (+18): NT producer +
// NT consumer = attn's feat read guaranteed HBM-cold; traded a 64MB L3-warm
// read for a 128MB cold one. Lesson: NT only where the marked load is the
// data's LAST reader.
// R12: exact revert to R10 (best measured), reproduction check.

typedef unsigned short u16;
typedef unsigned char u8;
typedef __attribute__((ext_vector_type(8))) __bf16 bf16x8;
typedef __attribute__((ext_vector_type(4))) float floatx4;
typedef __attribute__((ext_vector_type(16))) float floatx16;
typedef __attribute__((ext_vector_type(8))) int intx8;

__device__ __forceinline__ u16 f2bf(float f) {
    unsigned u = __float_as_uint(f);
    unsigned r = (u + 0x7FFFu + ((u >> 16) & 1u)) >> 16;
    return (u16)r;
}

// float -> OCP e4m3fn, RNE, saturate. Layout [s:1][e:4][m:3]: exp at BIT 3.
// Software path; hot loops use HW v_cvt_pk_fp8_f32 when available.
__device__ __forceinline__ unsigned f2e4m3(float x) {
    unsigned u = __float_as_uint(x);
    unsigned s = (u >> 31) << 7;
    float a = __uint_as_float(u & 0x7FFFFFFFu);
    if (a >= 448.f) return s | 0x7E;
    if (a < 0.03125f) {  // codes 0..16 are exactly k * 2^-9
        unsigned k = (unsigned)__float2int_rn(a * 512.f);
        return s | k;
    }
    unsigned b = __float_as_uint(a);
    unsigned lsb = (b >> 20) & 1u;
    b += 0x0007FFFFu + lsb;  // RNE to 3 mantissa bits (carry fixes exponent)
    unsigned ex = (b >> 23) - 120u;      // fp32 bias 127 -> e4m3 bias 7
    unsigned man = (b >> 20) & 7u;
    return s | (ex << 3) | man;
}

// 4x f32 -> packed e4m3 dword. HW packed cvt (2 inst) if the builtin exists.
__device__ __forceinline__ unsigned pack_fp8x4(floatx4 w) {
#if __has_builtin(__builtin_amdgcn_cvt_pk_fp8_f32)
    unsigned r = __builtin_amdgcn_cvt_pk_fp8_f32(w.x, w.y, 0u, false);
    r = __builtin_amdgcn_cvt_pk_fp8_f32(w.z, w.w, r, true);
    return r;
#else
    return f2e4m3(w.x) | (f2e4m3(w.y) << 8) |
           (f2e4m3(w.z) << 16) | (f2e4m3(w.w) << 24);
#endif
}

__device__ __forceinline__ void load_lds16(const void* g, void* l) {
    __builtin_amdgcn_global_load_lds(
        (const __attribute__((address_space(1))) void*)g,
        (__attribute__((address_space(3))) void*)l, 16, 0, 0);
}

__device__ __forceinline__ void unpack8(uint4 v, float* f) {
    f[0] = __uint_as_float(v.x << 16);
    f[1] = __uint_as_float(v.x & 0xFFFF0000u);
    f[2] = __uint_as_float(v.y << 16);
    f[3] = __uint_as_float(v.y & 0xFFFF0000u);
    f[4] = __uint_as_float(v.z << 16);
    f[5] = __uint_as_float(v.z & 0xFFFF0000u);
    f[6] = __uint_as_float(v.w << 16);
    f[7] = __uint_as_float(v.w & 0xFFFF0000u);
}

// ---------------------------------------------------------------------------
// k_front: weight-side prep, one launch.
//   ids [0,4096): z=0 WkT=Wk^T, z=1 WqT=Wq^T, z=2 WvT=Wv^T, z=3 Wob=cast(Wo)
//   ids [4096,4160): uk partials  u[h] += sum_o Wk[o,h]*bq[o]   (u pre-zeroed)
//   ids [4160,5184): cvec[j] = sum_o Wo[j,o]*bv[o] + bo[j]
__global__ __launch_bounds__(256) void k_front(const float* __restrict__ Wq,
                                               const float* __restrict__ Wk,
                                               const float* __restrict__ Wv,
                                               const float* __restrict__ Wo,
                                               const float* __restrict__ bq,
                                               const float* __restrict__ bv,
                                               const float* __restrict__ bo,
                                               u16* __restrict__ WqT,
                                               u16* __restrict__ WkT,
                                               u16* __restrict__ WvT,
                                               u16* __restrict__ Wob,
                                               float* __restrict__ u,
                                               float* __restrict__ cvec, int H) {
    __shared__ float t[32][33];
    __shared__ float red[4];
    const int id = blockIdx.x;
    if (id < 4096) {
        const int z = id >> 10;
        const int bx = (id & 31) * 32, by = ((id >> 5) & 31) * 32;
        const float* in = (z == 0) ? Wk : (z == 1) ? Wq : (z == 2) ? Wv : Wo;
        u16* out = (z == 0) ? WkT : (z == 1) ? WqT : (z == 2) ? WvT : Wob;
        const int x = threadIdx.x & 31, ty = threadIdx.x >> 5;
        if (z < 3) {
            for (int y = ty; y < 32; y += 8)
                t[y][x] = in[(size_t)(by + y) * H + bx + x];
            __syncthreads();
            for (int y = ty; y < 32; y += 8)
                out[(size_t)(bx + y) * H + by + x] = f2bf(t[x][y]);
        } else {
            for (int y = ty; y < 32; y += 8)
                out[(size_t)(by + y) * H + bx + x] =
                    f2bf(in[(size_t)(by + y) * H + bx + x]);
        }
    } else if (id < 4160) {
        const int r = id - 4096;                 // (H/256)=4 x-blocks, 16 y
        const int h = (r & 3) * 256 + threadIdx.x;
        const int chunk = H / 16, o0 = (r >> 2) * chunk;
        float s = 0.f;
        for (int o = o0; o < o0 + chunk; ++o) s += bq[o] * Wk[(size_t)o * H + h];
        atomicAdd(&u[h], s);
    } else {
        const int j = id - 4160;
        const int lane = threadIdx.x & 63, wv = threadIdx.x >> 6;
        float s = 0.f;
        for (int o = threadIdx.x; o < H; o += 256)
            s += Wo[(size_t)j * H + o] * bv[o];
        for (int off = 32; off > 0; off >>= 1) s += __shfl_down(s, off);
        if (lane == 0) red[wv] = s;
        __syncthreads();
        if (threadIdx.x == 0) cvec[j] = red[0] + red[1] + red[2] + red[3] + bo[j];
    }
}

// ---------------------------------------------------------------------------
// bf16 BT-GEMM body (R2/R5-verified). OUTMODE 0: fp32+bias; 1: bf16(+bias);
// 2: dual-write bf16 (Cp) AND fp8(32x) (Cp8, skipped if null).
// Single-buffered (16 KB): k_mid's cast blocks share this kernel and need
// the LDS headroom for occupancy.
struct GemmLds { u16 As[128 * 32]; u16 Bs[128 * 32]; };

template <int OUTMODE>
__device__ __forceinline__ void gemm_body(GemmLds& S,
                                          const u16* __restrict__ A,
                                          const u16* __restrict__ Bw,
                                          void* __restrict__ Cp,
                                          u8* __restrict__ Cp8,
                                          const float* __restrict__ bias,
                                          int M, int N, int K,
                                          int bx, int by) {
    u16* As = S.As;
    u16* Bs = S.Bs;
    const int tid = threadIdx.x, lane = tid & 63, wv = tid >> 6;
    const int m0 = bx * 128, n0 = by * 128;
    const int wm = (wv >> 1) * 64, wn = (wv & 1) * 64;

    floatx4 acc[4][4];
#pragma unroll
    for (int i = 0; i < 4; ++i)
#pragma unroll
        for (int j = 0; j < 4; ++j) acc[i][j] = (floatx4){0.f, 0.f, 0.f, 0.f};

    const int srow = lane >> 2;
    const int scol = (((lane & 3) ^ ((lane >> 3) & 3)) * 8);
    const u16* gA = A + (size_t)(m0 + srow) * K + scol;
    const u16* gB = Bw + (size_t)(n0 + srow) * K + scol;
    const int r = lane & 15, q = lane >> 4;
    const int cph = q ^ ((r >> 1) & 3);

    for (int kt = 0; kt < K; kt += 32) {
#pragma unroll
        for (int c = 0; c < 2; ++c) {
            int chunk = wv * 2 + c;
            load_lds16(gA + (size_t)(chunk * 16) * K + kt, &As[chunk * 16 * 32]);
            load_lds16(gB + (size_t)(chunk * 16) * K + kt, &Bs[chunk * 16 * 32]);
        }
        __syncthreads();
        bf16x8 af[4], bfr[4];
#pragma unroll
        for (int i = 0; i < 4; ++i) {
            af[i] = *(const bf16x8*)&As[(wm + i * 16 + r) * 32 + cph * 8];
            bfr[i] = *(const bf16x8*)&Bs[(wn + i * 16 + r) * 32 + cph * 8];
        }
#pragma unroll
        for (int i = 0; i < 4; ++i)
#pragma unroll
            for (int j = 0; j < 4; ++j)
                acc[i][j] = __builtin_amdgcn_mfma_f32_16x16x32_bf16(af[i], bfr[j], acc[i][j], 0, 0, 0);
        __syncthreads();
    }

    const int cc = lane & 15, cr = (lane >> 4) * 4;
#pragma unroll
    for (int i = 0; i < 4; ++i)
#pragma unroll
        for (int j = 0; j < 4; ++j) {
            int col = n0 + wn + j * 16 + cc;
            float badd = bias ? bias[col] : 0.f;
#pragma unroll
            for (int r0 = 0; r0 < 4; ++r0) {
                int row = m0 + wm + i * 16 + cr + r0;
                float v = acc[i][j][r0] + badd;
                if (OUTMODE == 0) ((float*)Cp)[(size_t)row * N + col] = v;
                else ((u16*)Cp)[(size_t)row * N + col] = f2bf(v);
                if (OUTMODE == 2 && Cp8)
                    Cp8[(size_t)row * N + col] = (u8)f2e4m3(32.f * v);
            }
        }
}

// ---------------------------------------------------------------------------
// k_mid: weight GEMMs + feature cast in ONE launch (R6-proven best structure).
//   ids [0,128): GEMM blocks. z=0: Aw = bf16(Wk^T Wq) (+ Awf8 = fp8(32x));
//                z=1: Wov = Wo Wv.
//   ids [128, 128+2048): grid-stride cast, CH=4096 floats/block-iter,
//   4 independent NONTEMPORAL float4 loads in flight (feat is read-once;
//   don't evict the Xf8/Xb lines score8/attn re-read), HW packed fp8 cvt.
__global__ __launch_bounds__(256) void k_mid(const float* __restrict__ feat,
                                             u16* __restrict__ Xb,
                                             u8* __restrict__ Xf8, long n,
                                             const u16* __restrict__ WkT,
                                             const u16* __restrict__ WqT,
                                             u16* __restrict__ Aw,
                                             u8* __restrict__ Awf8,
                                             const u16* __restrict__ Wob,
                                             const u16* __restrict__ WvT,
                                             u16* __restrict__ Wov, int H) {
    __shared__ __align__(16) GemmLds S;
    const int id = blockIdx.x;
    if (id < 128) {
        const int z = id >> 6, bx = (id & 63) & 7, by = (id & 63) >> 3;
        if (z == 0)
            gemm_body<2>(S, WkT, WqT, Aw, Awf8, nullptr, H, H, H, bx, by);
        else
            gemm_body<1>(S, Wob, WvT, Wov, nullptr, nullptr, H, H, H, bx, by);
        return;
    }
    const int tid = threadIdx.x;
    const long nCast = (long)(gridDim.x - 128);
    const long CH = 4096;  // floats per block-iter (256 thr x 16)
    for (long s = (long)(id - 128) * CH; s < n; s += nCast * CH) {
        const floatx4* src = (const floatx4*)(feat + s) + tid;
        floatx4 v[4];
#pragma unroll
        for (int k = 0; k < 4; ++k)
            v[k] = __builtin_nontemporal_load(src + k * 256);  // 4 in flight, NT
        ushort4* db = (ushort4*)(Xb + s) + tid;
#pragma unroll
        for (int k = 0; k < 4; ++k) {
            ushort4 o;
            o.x = f2bf(v[k].x); o.y = f2bf(v[k].y);
            o.z = f2bf(v[k].z); o.w = f2bf(v[k].w);
            db[k * 256] = o;
        }
        if (Xf8) {
            unsigned* df = (unsigned*)(Xf8 + s) + tid;
#pragma unroll
            for (int k = 0; k < 4; ++k) df[k * 256] = pack_fp8x4(v[k]);
        }
    }
}

// bf16 fallback score GEMM: G = bf16(X Aw^T + uk)
__global__ __launch_bounds__(256) void k_score(const u16* __restrict__ X,
                                               const u16* __restrict__ Aw,
                                               u16* __restrict__ G,
                                               const float* __restrict__ uk,
                                               int Mr, int N, int K) {
    __shared__ __align__(16) GemmLds S;
    gemm_body<1>(S, X, Aw, G, nullptr, uk, Mr, N, K, blockIdx.x, blockIdx.y);
}

// out = Y @ Wov^T + cvec (fp32 out)
__global__ __launch_bounds__(256) void k_out(const u16* __restrict__ A,
                                             const u16* __restrict__ Bw,
                                             float* __restrict__ C,
                                             const float* __restrict__ bias,
                                             int M, int N, int K) {
    __shared__ __align__(16) GemmLds S;
    gemm_body<0>(S, A, Bw, C, nullptr, bias, M, N, K, blockIdx.x, blockIdx.y);
}

// ---------------------------------------------------------------------------
// MX-fp8 score GEMM via mfma_scale_f32_32x32x64_f8f6f4, unit E8M0 scales.
// 2-phase double-buffer (R6): prefetch tile t+1 into buf^1 BEFORE computing
// tile t; ONE __syncthreads per tile (implicit vmcnt(0)+lgkmcnt(0) drain).
// A/B lane layout: m = lane&31, k = (lane>>5)*32 + byte. C/D (guide-verified):
// col = lane&31, row = (reg&3) + 8*(reg>>2) + 4*(lane>>5).
// XCD-aware bijective swizzle (nwg=2048, %8==0).
// G[r,h'] = 32*(sum_h X[r,h]*Aw[h',h] + uk[h']), bf16 out.
__global__ __launch_bounds__(256) void k_score8(const u8* __restrict__ Af8,
                                                const u8* __restrict__ Bf8,
                                                u16* __restrict__ G,
                                                const float* __restrict__ uk,
                                                int Mr, int N, int K) {
    __shared__ __align__(16) u8 As[2][128 * 64];
    __shared__ __align__(16) u8 Bs[2][128 * 64];
    const int tid = threadIdx.x, lane = tid & 63, wv = tid >> 6;

    // XCD swizzle: orig%8 == XCD id under round-robin dispatch.
    const int nbx = gridDim.x;                       // 8
    const int nwg = nbx * gridDim.y;                 // 2048 (divisible by 8)
    const int orig = blockIdx.y * nbx + blockIdx.x;
    const int cpx = nwg >> 3;                        // blocks per XCD
    const int id = (orig & 7) * cpx + (orig >> 3);
    const int n0 = (id % nbx) * 128, m0 = (id / nbx) * 128;
    const int wm = (wv >> 1) * 64, wn = (wv & 1) * 64;

    floatx16 acc[2][2];
#pragma unroll
    for (int i = 0; i < 2; ++i)
#pragma unroll
        for (int j = 0; j < 2; ++j)
            acc[i][j] = (floatx16){0.f, 0.f, 0.f, 0.f, 0.f, 0.f, 0.f, 0.f,
                                   0.f, 0.f, 0.f, 0.f, 0.f, 0.f, 0.f, 0.f};

    const int srow = lane >> 2;
    const int scol = 16 * ((lane & 3) ^ ((lane >> 3) & 3));
    const u8* gA = Af8 + (size_t)(m0 + srow) * K + scol;
    const u8* gB = Bf8 + (size_t)(n0 + srow) * K + scol;

    // frag read geometry: lane needs k-bytes [q2*32, q2*32+32) of row r32,
    // i.e. 16B chunks {2q2, 2q2+1}, XOR'd by the staging swizzle (r32>>1)&3.
    const int r32 = lane & 31, q2 = lane >> 5;
    const int sw = (r32 >> 1) & 3;
    const int c0 = (2 * q2) ^ sw, c1 = (2 * q2 + 1) ^ sw;

    union frag32 { intx8 v; uint4 q[2]; };

    auto stage = [&](int buf, int kt) {
#pragma unroll
        for (int c = 0; c < 2; ++c) {
            int chunk = wv * 2 + c;
            load_lds16(gA + (size_t)(chunk * 16) * K + kt, &As[buf][chunk * 16 * 64]);
            load_lds16(gB + (size_t)(chunk * 16) * K + kt, &Bs[buf][chunk * 16 * 64]);
        }
    };

    stage(0, 0);
    __syncthreads();
    int cur = 0;
    for (int kt = 0; kt < K; kt += 64) {
        if (kt + 64 < K) stage(cur ^ 1, kt + 64);  // next tile in flight
        frag32 fa[2], fb[2];
#pragma unroll
        for (int i = 0; i < 2; ++i) {
            const u8* pa = &As[cur][(wm + i * 32 + r32) * 64];
            const u8* pb = &Bs[cur][(wn + i * 32 + r32) * 64];
            fa[i].q[0] = *(const uint4*)(pa + c0 * 16);
            fa[i].q[1] = *(const uint4*)(pa + c1 * 16);
            fb[i].q[0] = *(const uint4*)(pb + c0 * 16);
            fb[i].q[1] = *(const uint4*)(pb + c1 * 16);
        }
#pragma unroll
        for (int i = 0; i < 2; ++i)
#pragma unroll
            for (int j = 0; j < 2; ++j)
                acc[i][j] = __builtin_amdgcn_mfma_scale_f32_32x32x64_f8f6f4(
                    fa[i].v, fb[j].v, acc[i][j], 0, 0,
                    0, 0x7F7F7F7F, 0, 0x7F7F7F7F);
        __syncthreads();  // drains vmcnt (next tile landed) + syncs ds_reads
        cur ^= 1;
    }

    const int cc = lane & 31, rbase = 4 * (lane >> 5);
#pragma unroll
    for (int i = 0; i < 2; ++i)
#pragma unroll
        for (int j = 0; j < 2; ++j) {
            int col = n0 + wn + j * 32 + cc;
            float badd = 32.f * uk[col];
#pragma unroll
            for (int reg = 0; reg < 16; ++reg) {
                int row = m0 + wm + i * 32 + (reg & 3) + 8 * (reg >> 2) + rbase;
                G[(size_t)row * N + col] = f2bf(acc[i][j][reg] + badd);
            }
        }
}

// ---------------------------------------------------------------------------
// Per-batch attention, one wave per batch; X retained in registers.
// gscale folds G's scale into the softmax: bf16 G -> conf/32; fp8 G -> conf/1024.
__global__ __launch_bounds__(256) void k_attn(const u16* __restrict__ G,
                                              const u16* __restrict__ X,
                                              const float* __restrict__ conf,
                                              u16* __restrict__ Y, float gscale,
                                              int H) {
    const int lane = threadIdx.x & 63, wv = threadIdx.x >> 6;
    const int b = blockIdx.x * 4 + wv;
    const u16* Gb = G + (size_t)b * 4 * H;
    const u16* Xb = X + (size_t)b * 4 * H;

    uint4 xraw[2][4];
    float s[16];
#pragma unroll
    for (int t = 0; t < 16; ++t) s[t] = 0.f;

#pragma unroll
    for (int c = 0; c < 2; ++c) {
        const int off = c * 512 + lane * 8;
#pragma unroll
        for (int rr = 0; rr < 4; ++rr)
            xraw[c][rr] = *(const uint4*)(Xb + rr * H + off);
        float xv[4][8];
#pragma unroll
        for (int rr = 0; rr < 4; ++rr) unpack8(xraw[c][rr], xv[rr]);
#pragma unroll
        for (int m = 0; m < 4; ++m) {
            uint4 gl = *(const uint4*)(Gb + m * H + off);
            float gv[8];
            unpack8(gl, gv);
#pragma unroll
            for (int n = 0; n < 4; ++n) {
                float a = 0.f;
#pragma unroll
                for (int j = 0; j < 8; ++j) a += gv[j] * xv[n][j];
                s[m * 4 + n] += a;
            }
        }
    }
#pragma unroll
    for (int t = 0; t < 16; ++t) {
#pragma unroll
        for (int mask = 32; mask; mask >>= 1) s[t] += __shfl_xor(s[t], mask);
    }
    float w[4] = {0.f, 0.f, 0.f, 0.f};
#pragma unroll
    for (int m = 0; m < 4; ++m) {
        float cm = conf[(size_t)b * 4 + m] * gscale;
        float sc[4], mx = -1e30f;
#pragma unroll
        for (int n = 0; n < 4; ++n) {
            sc[n] = s[m * 4 + n] * cm;
            mx = fmaxf(mx, sc[n]);
        }
        float e[4], ssum = 0.f;
#pragma unroll
        for (int n = 0; n < 4; ++n) { e[n] = __expf(sc[n] - mx); ssum += e[n]; }
        float inv = 0.25f / ssum;
#pragma unroll
        for (int n = 0; n < 4; ++n) w[n] += e[n] * inv;
    }
#pragma unroll
    for (int c = 0; c < 2; ++c) {
        const int off = c * 512 + lane * 8;
        float xv[4][8];
#pragma unroll
        for (int rr = 0; rr < 4; ++rr) unpack8(xraw[c][rr], xv[rr]);
        float y[8];
#pragma unroll
        for (int j = 0; j < 8; ++j)
            y[j] = w[0] * xv[0][j] + w[1] * xv[1][j] + w[2] * xv[2][j] + w[3] * xv[3][j];
        uint4 res;
        res.x = (unsigned)f2bf(y[0]) | ((unsigned)f2bf(y[1]) << 16);
        res.y = (unsigned)f2bf(y[2]) | ((unsigned)f2bf(y[3]) << 16);
        res.z = (unsigned)f2bf(y[4]) | ((unsigned)f2bf(y[5]) << 16);
        res.w = (unsigned)f2bf(y[6]) | ((unsigned)f2bf(y[7]) << 16);
        *(uint4*)(Y + (size_t)b * H + off) = res;
    }
}

// ---------------------------------------------------------------------------
extern "C" void kernel_launch(void* const* d_in, const int* in_sizes, int n_in,
                              void* d_out, int out_size, void* d_ws, size_t ws_size,
                              hipStream_t stream) {
    const int H = 1024, M = 4;
    const int B = in_sizes[0] / (H * M);
    const long BMH = (long)B * M * H;

    const float* feat = (const float*)d_in[0];
    const float* conf = (const float*)d_in[1];
    const float* Wq = (const float*)d_in[2];
    const float* bq = (const float*)d_in[3];
    const float* Wk = (const float*)d_in[4];
    const float* Wv = (const float*)d_in[6];
    const float* bv = (const float*)d_in[7];
    const float* Wo = (const float*)d_in[8];
    const float* bo = (const float*)d_in[9];

    char* ws = (char*)d_ws;
    size_t off = 0;
    auto alloc = [&](size_t bytes) {
        void* p = ws + off;
        off += (bytes + 255) & ~(size_t)255;
        return p;
    };
    // base (R5-proven footprint)
    u16* Xb    = (u16*)alloc((size_t)BMH * 2);   //  64 MB
    u16* G     = (u16*)alloc((size_t)BMH * 2);   //  64 MB
    u16* Yb    = (u16*)alloc((size_t)B * H * 2); //  16 MB
    u16* WkT   = (u16*)alloc((size_t)H * H * 2);
    u16* WqT   = (u16*)alloc((size_t)H * H * 2);
    u16* WvT   = (u16*)alloc((size_t)H * H * 2);
    u16* Wob   = (u16*)alloc((size_t)H * H * 2);
    u16* Aw    = (u16*)alloc((size_t)H * H * 2);
    u16* Wov   = (u16*)alloc((size_t)H * H * 2);
    float* u    = (float*)alloc((size_t)H * 4);
    float* cvec = (float*)alloc((size_t)H * 4);
    // fp8 extras (+33 MB) — only used if they fit
    u8* Xf8  = (u8*)alloc((size_t)BMH);
    u8* Awf8 = (u8*)alloc((size_t)H * H);
    const bool use_fp8 = (off <= ws_size);
    (void)n_in; (void)out_size;

    // 1. weight-side prep (one launch) — u zeroed first for the uk atomics
    hipMemsetAsync(u, 0, (size_t)H * 4, stream);
    k_front<<<4096 + 64 + H, 256, 0, stream>>>(
        Wq, Wk, Wv, Wo, bq, bv, bo, WqT, WkT, WvT, Wob, u, cvec, H);

    // 2. weight GEMMs overlapped with grid-stride feature cast (one launch)
    k_mid<<<128 + 2048, 256, 0, stream>>>(
        feat, Xb, use_fp8 ? Xf8 : nullptr, BMH,
        WkT, WqT, Aw, use_fp8 ? Awf8 : nullptr, Wob, WvT, Wov, H);

    // 3. score GEMM
    if (use_fp8) {
        k_score8<<<dim3(H / 128, B * M / 128), 256, 0, stream>>>(
            Xf8, Awf8, G, u, B * M, H, H);
    } else {
        k_score<<<dim3(B * M / 128, H / 128), 256, 0, stream>>>(
            Xb, Aw, G, u, B * M, H, H);
    }

    // 4. attention -> Y  (fp8 G carries a 32x scale: 1/(32*32) vs 1/32)
    k_attn<<<B / 4, 256, 0, stream>>>(G, Xb, conf, Yb,
                                      use_fp8 ? 0.0009765625f : 0.03125f, H);

    // 5. out = Y @ Wov^T + cvec
    k_out<<<dim3(B / 128, H / 128), 256, 0, stream>>>(Yb, Wov, (float*)d_out, cvec, B, H, H);
}